// Round 1
// baseline (350.819 us; speedup 1.0000x reference)
//
#include <hip/hip_runtime.h>

#define HW 4608      // 48*96
#define NB 16        // batch
#define CC 256       // channels
#define SS 64        // states
#define EPS 1e-5f

// ---------------- K1: edge gate = sigmoid(e1 - e0) ----------------
__global__ __launch_bounds__(256) void k_gate(const float* __restrict__ edge,
                                              float* __restrict__ gate) {
    int i = blockIdx.x * 256 + threadIdx.x;      // i over NB*HW = 73728
    int n = i / HW, k = i - n * HW;
    float e0 = edge[(size_t)(n * 2 + 0) * HW + k];
    float e1 = edge[(size_t)(n * 2 + 1) * HW + k];
    gate[i] = 1.0f / (1.0f + __expf(e0 - e1));
}

// ---------------- K2: xs = Ws@x + bs ; p = (Wp@x + bp)*(1+gate) ----------------
// grid (HW/64=72, NB), block 256. Tile: 64 s x 64 k, reduce over C=256.
__global__ __launch_bounds__(256) void k_proj(const float* __restrict__ x,
                                              const float* __restrict__ Ws,
                                              const float* __restrict__ bs,
                                              const float* __restrict__ Wp,
                                              const float* __restrict__ bp,
                                              const float* __restrict__ gate,
                                              float* __restrict__ xs,
                                              float* __restrict__ pc) {
    __shared__ __align__(16) float xsm[16][64];
    __shared__ __align__(16) float wsT[16][64];
    __shared__ __align__(16) float wpT[16][64];
    int n = blockIdx.y;
    int k0 = blockIdx.x * 64;
    int tid = threadIdx.x;
    int ts = tid >> 4, tk = tid & 15;
    float accS[4][4] = {};
    float accP[4][4] = {};
    for (int c0 = 0; c0 < CC; c0 += 16) {
#pragma unroll
        for (int i = 0; i < 4; i++) {
            int idx = tid + i * 256;                 // 0..1023
            int cc = idx >> 6, kl = idx & 63;
            xsm[cc][kl] = x[((size_t)n * CC + c0 + cc) * HW + k0 + kl];
        }
#pragma unroll
        for (int i = 0; i < 4; i++) {
            int idx = tid + i * 256;                 // 0..1023
            int s = idx >> 4, cc = idx & 15;
            wsT[cc][s] = Ws[s * CC + c0 + cc];
            wpT[cc][s] = Wp[s * CC + c0 + cc];
        }
        __syncthreads();
#pragma unroll
        for (int cc = 0; cc < 16; cc++) {
            float4 xv = *(const float4*)&xsm[cc][tk * 4];
            float4 av = *(const float4*)&wsT[cc][ts * 4];
            float4 pv = *(const float4*)&wpT[cc][ts * 4];
            float xa[4] = {xv.x, xv.y, xv.z, xv.w};
            float aa[4] = {av.x, av.y, av.z, av.w};
            float pa[4] = {pv.x, pv.y, pv.z, pv.w};
#pragma unroll
            for (int i = 0; i < 4; i++)
#pragma unroll
                for (int j = 0; j < 4; j++) {
                    accS[i][j] += aa[i] * xa[j];
                    accP[i][j] += pa[i] * xa[j];
                }
        }
        __syncthreads();
    }
    float4 g = *(const float4*)&gate[n * HW + k0 + tk * 4];
    float ga[4] = {1.f + g.x, 1.f + g.y, 1.f + g.z, 1.f + g.w};
#pragma unroll
    for (int i = 0; i < 4; i++) {
        int s = ts * 4 + i;
        float bsv = bs[s], bpv = bp[s];
        float4 o1, o2;
        o1.x = accS[i][0] + bsv; o1.y = accS[i][1] + bsv;
        o1.z = accS[i][2] + bsv; o1.w = accS[i][3] + bsv;
        o2.x = (accP[i][0] + bpv) * ga[0]; o2.y = (accP[i][1] + bpv) * ga[1];
        o2.z = (accP[i][2] + bpv) * ga[2]; o2.w = (accP[i][3] + bpv) * ga[3];
        size_t off = ((size_t)n * SS + s) * HW + k0 + tk * 4;
        *(float4*)&xs[off] = o1;
        *(float4*)&pc[off] = o2;
    }
}

// ---------------- K3: softmax along HW per (n,s) row ----------------
__global__ __launch_bounds__(256) void k_softmax(float* __restrict__ pc) {
    __shared__ float row[HW];
    __shared__ float red[256];
    int r = blockIdx.x;                 // n*64 + s
    float* p = pc + (size_t)r * HW;
    int tid = threadIdx.x;
    float mx = -1e30f;
#pragma unroll
    for (int i = 0; i < 18; i++) {
        float v = p[tid + i * 256];
        row[tid + i * 256] = v;
        mx = fmaxf(mx, v);
    }
    red[tid] = mx;
    __syncthreads();
    for (int off = 128; off > 0; off >>= 1) {
        if (tid < off) red[tid] = fmaxf(red[tid], red[tid + off]);
        __syncthreads();
    }
    mx = red[0];
    __syncthreads();
    float sm = 0.f;
#pragma unroll
    for (int i = 0; i < 18; i++) {
        float e = __expf(row[tid + i * 256] - mx);
        row[tid + i * 256] = e;
        sm += e;
    }
    red[tid] = sm;
    __syncthreads();
    for (int off = 128; off > 0; off >>= 1) {
        if (tid < off) red[tid] += red[tid + off];
        __syncthreads();
    }
    float inv = 1.0f / red[0];
#pragma unroll
    for (int i = 0; i < 18; i++) p[tid + i * 256] = row[tid + i * 256] * inv;
}

// ---------------- K4: xn = xs@combT, G = comb@combT (split-K + atomics) ----------------
// grid (8, NB), each block: 576 k positions. Accumulators 4x4 per thread for both.
__global__ __launch_bounds__(256) void k_graph(const float* __restrict__ xs,
                                               const float* __restrict__ pc,
                                               float* __restrict__ xn,
                                               float* __restrict__ G) {
    __shared__ __align__(16) float xsT[32 * 68];
    __shared__ __align__(16) float cbT[32 * 68];
    int n = blockIdx.y;
    int k0 = blockIdx.x * 576;
    int tid = threadIdx.x;
    int ts = tid >> 4, tk = tid & 15;
    float aXn[4][4] = {};
    float aG[4][4] = {};
    for (int sub = 0; sub < 18; sub++) {
        int kb = k0 + sub * 32;
#pragma unroll
        for (int i = 0; i < 8; i++) {
            int idx = tid + i * 256;            // 0..2047
            int s = idx >> 5, kk = idx & 31;
            size_t off = ((size_t)n * SS + s) * HW + kb + kk;
            xsT[kk * 68 + s] = xs[off];
            cbT[kk * 68 + s] = pc[off];
        }
        __syncthreads();
#pragma unroll
        for (int kk = 0; kk < 32; kk++) {
            float4 a4 = *(const float4*)&xsT[kk * 68 + ts * 4];
            float4 b4 = *(const float4*)&cbT[kk * 68 + tk * 4];
            float4 c4 = *(const float4*)&cbT[kk * 68 + ts * 4];
            float a[4] = {a4.x, a4.y, a4.z, a4.w};
            float b[4] = {b4.x, b4.y, b4.z, b4.w};
            float c[4] = {c4.x, c4.y, c4.z, c4.w};
#pragma unroll
            for (int i = 0; i < 4; i++)
#pragma unroll
                for (int j = 0; j < 4; j++) {
                    aXn[i][j] += a[i] * b[j];
                    aG[i][j] += c[i] * b[j];
                }
        }
        __syncthreads();
    }
#pragma unroll
    for (int i = 0; i < 4; i++)
#pragma unroll
        for (int j = 0; j < 4; j++) {
            int o = n * 4096 + (ts * 4 + i) * 64 + tk * 4 + j;
            atomicAdd(&xn[o], aXn[i][j]);
            atomicAdd(&G[o], aG[i][j]);
        }
}

// ---------------- K5: GCN + fold We:  M[n] = We @ relu(W2 @ (xn@W1^T - xn)) ----------------
// grid NB, block 256. All intermediates in LDS.
__global__ __launch_bounds__(256) void k_gcn(const float* __restrict__ xn,
                                             const float* __restrict__ W1,
                                             const float* __restrict__ W2,
                                             const float* __restrict__ We,
                                             float* __restrict__ M) {
    __shared__ __align__(16) float A[64 * 68];
    __shared__ __align__(16) float B[64 * 68];
    __shared__ __align__(16) float Cb[64 * 68];
    int n = blockIdx.x;
    int tid = threadIdx.x;
    int t0 = tid >> 4, t1 = tid & 15;
    // load xn^T into A (A[j][s] = xn[s][j]), W1^T into B (B[j][i] = W1[i][j])
#pragma unroll
    for (int i = 0; i < 16; i++) {
        int idx = tid + i * 256;               // 0..4095
        int r = idx >> 6, cth = idx & 63;
        A[cth * 68 + r] = xn[n * 4096 + idx];
        B[cth * 68 + r] = W1[idx];
    }
    __syncthreads();
    // phase1: h1[s][i] = sum_j A[j][s]*B[j][i] - xn[s][i]  -> Cb[s][i]
    {
        float acc[4][4] = {};
        for (int j = 0; j < 64; j++) {
            float4 a4 = *(const float4*)&A[j * 68 + t0 * 4];
            float4 b4 = *(const float4*)&B[j * 68 + t1 * 4];
            float a[4] = {a4.x, a4.y, a4.z, a4.w};
            float b[4] = {b4.x, b4.y, b4.z, b4.w};
#pragma unroll
            for (int p = 0; p < 4; p++)
#pragma unroll
                for (int q = 0; q < 4; q++) acc[p][q] += a[p] * b[q];
        }
#pragma unroll
        for (int p = 0; p < 4; p++)
#pragma unroll
            for (int q = 0; q < 4; q++) {
                acc[p][q] -= A[(t1 * 4 + q) * 68 + (t0 * 4 + p)];
                Cb[(t0 * 4 + p) * 68 + t1 * 4 + q] = acc[p][q];
            }
    }
    __syncthreads();
    // load W2^T into B
#pragma unroll
    for (int i = 0; i < 16; i++) {
        int idx = tid + i * 256;
        int r = idx >> 6, cth = idx & 63;
        B[cth * 68 + r] = W2[idx];
    }
    __syncthreads();
    // phase2: h2[i][k] = relu(sum_j B[j][i]*Cb[j][k]) -> A[i][k]
    {
        float acc[4][4] = {};
        for (int j = 0; j < 64; j++) {
            float4 a4 = *(const float4*)&B[j * 68 + t0 * 4];
            float4 b4 = *(const float4*)&Cb[j * 68 + t1 * 4];
            float a[4] = {a4.x, a4.y, a4.z, a4.w};
            float b[4] = {b4.x, b4.y, b4.z, b4.w};
#pragma unroll
            for (int p = 0; p < 4; p++)
#pragma unroll
                for (int q = 0; q < 4; q++) acc[p][q] += a[p] * b[q];
        }
        __syncthreads();
#pragma unroll
        for (int p = 0; p < 4; p++)
#pragma unroll
            for (int q = 0; q < 4; q++)
                A[(t0 * 4 + p) * 68 + t1 * 4 + q] = fmaxf(acc[p][q], 0.f);
    }
    __syncthreads();
    // phase3: M[c][t] = sum_j We[c][j]*h2[j][t], chunks of 64 c
    for (int cc = 0; cc < 4; cc++) {
#pragma unroll
        for (int i = 0; i < 16; i++) {
            int idx = tid + i * 256;
            int c = idx >> 6, j = idx & 63;
            B[j * 68 + c] = We[(cc * 64 + c) * 64 + j];
        }
        __syncthreads();
        float acc[4][4] = {};
        for (int j = 0; j < 64; j++) {
            float4 a4 = *(const float4*)&B[j * 68 + t0 * 4];
            float4 b4 = *(const float4*)&A[j * 68 + t1 * 4];
            float a[4] = {a4.x, a4.y, a4.z, a4.w};
            float b[4] = {b4.x, b4.y, b4.z, b4.w};
#pragma unroll
            for (int p = 0; p < 4; p++)
#pragma unroll
                for (int q = 0; q < 4; q++) acc[p][q] += a[p] * b[q];
        }
#pragma unroll
        for (int p = 0; p < 4; p++) {
            float4 st;
            st.x = acc[p][0]; st.y = acc[p][1]; st.z = acc[p][2]; st.w = acc[p][3];
            *(float4*)&M[((size_t)n * CC + cc * 64 + t0 * 4 + p) * 64 + t1 * 4] = st;
        }
        __syncthreads();
    }
}

// ---------------- K6: BN stats via closed forms -> scale/bias per channel ----------------
// sum_k ext = sum_s M ; sum_k ext^2 = m^T G m. grid CC, block 256.
__global__ __launch_bounds__(256) void k_stats(const float* __restrict__ M,
                                               const float* __restrict__ G,
                                               const float* __restrict__ gamma,
                                               const float* __restrict__ beta,
                                               float* __restrict__ sc,
                                               float* __restrict__ bi) {
    __shared__ float ms[64];
    __shared__ float red[256];
    int c = blockIdx.x;
    int tid = threadIdx.x;
    float qa = 0.f, sa = 0.f;
    for (int n = 0; n < NB; n++) {
        if (tid < 64) ms[tid] = M[((size_t)n * CC + c) * 64 + tid];
        __syncthreads();
#pragma unroll
        for (int p = 0; p < 16; p++) {
            int e = p * 256 + tid;
            int s = e >> 6, u = e & 63;
            qa += ms[s] * ms[u] * G[n * 4096 + e];
        }
        if ((tid & 63) == 0) {
#pragma unroll
            for (int p = 0; p < 16; p++) {
                int e = p * 256 + tid;
                sa += ms[e >> 6];
            }
        }
        __syncthreads();
    }
    red[tid] = qa;
    __syncthreads();
    for (int off = 128; off > 0; off >>= 1) {
        if (tid < off) red[tid] += red[tid + off];
        __syncthreads();
    }
    float qtot = red[0];
    __syncthreads();
    red[tid] = sa;
    __syncthreads();
    for (int off = 128; off > 0; off >>= 1) {
        if (tid < off) red[tid] += red[tid + off];
        __syncthreads();
    }
    float stot = red[0];
    if (tid == 0) {
        const float invM = 1.0f / ((float)NB * (float)HW);
        float mean = stot * invM;
        float var = qtot * invM - mean * mean;
        float s = gamma[c] * rsqrtf(var + EPS);
        sc[c] = s;
        bi[c] = beta[c] - s * mean;
    }
}

// ---------------- K7: out = x + sc[c] * (M[n] @ comb)[c,k] + bi[c] ----------------
// grid (36, 4, NB): 128 k x 64 c tile per block.
__global__ __launch_bounds__(256) void k_out(const float* __restrict__ x,
                                             const float* __restrict__ M,
                                             const float* __restrict__ pc,
                                             const float* __restrict__ sc,
                                             const float* __restrict__ bi,
                                             float* __restrict__ out) {
    __shared__ __align__(16) float MT[16 * 68];
    __shared__ __align__(16) float cb[16 * 128];
    int k0 = blockIdx.x * 128;
    int c0 = blockIdx.y * 64;
    int n = blockIdx.z;
    int tid = threadIdx.x;
    int tc = tid >> 4, tk = tid & 15;
    float acc[4][8] = {};
    for (int s0 = 0; s0 < 64; s0 += 16) {
#pragma unroll
        for (int i = 0; i < 4; i++) {
            int idx = tid + i * 256;              // 0..1023
            int cL = idx >> 4, sj = idx & 15;
            MT[sj * 68 + cL] = M[((size_t)n * CC + c0 + cL) * 64 + s0 + sj];
        }
#pragma unroll
        for (int i = 0; i < 8; i++) {
            int idx = tid + i * 256;              // 0..2047
            int sj = idx >> 7, kk = idx & 127;
            cb[sj * 128 + kk] = pc[((size_t)n * SS + s0 + sj) * HW + k0 + kk];
        }
        __syncthreads();
#pragma unroll
        for (int sj = 0; sj < 16; sj++) {
            float4 a4 = *(const float4*)&MT[sj * 68 + tc * 4];
            float4 b0 = *(const float4*)&cb[sj * 128 + tk * 8];
            float4 b1 = *(const float4*)&cb[sj * 128 + tk * 8 + 4];
            float a[4] = {a4.x, a4.y, a4.z, a4.w};
            float b[8] = {b0.x, b0.y, b0.z, b0.w, b1.x, b1.y, b1.z, b1.w};
#pragma unroll
            for (int i = 0; i < 4; i++)
#pragma unroll
                for (int j = 0; j < 8; j++) acc[i][j] += a[i] * b[j];
        }
        __syncthreads();
    }
#pragma unroll
    for (int i = 0; i < 4; i++) {
        int c = c0 + tc * 4 + i;
        float s = sc[c], bv = bi[c];
        size_t base = ((size_t)n * CC + c) * HW + k0 + tk * 8;
        float4 x0 = *(const float4*)&x[base];
        float4 x1 = *(const float4*)&x[base + 4];
        float4 o0, o1;
        o0.x = x0.x + s * acc[i][0] + bv;
        o0.y = x0.y + s * acc[i][1] + bv;
        o0.z = x0.z + s * acc[i][2] + bv;
        o0.w = x0.w + s * acc[i][3] + bv;
        o1.x = x1.x + s * acc[i][4] + bv;
        o1.y = x1.y + s * acc[i][5] + bv;
        o1.z = x1.z + s * acc[i][6] + bv;
        o1.w = x1.w + s * acc[i][7] + bv;
        *(float4*)&out[base] = o0;
        *(float4*)&out[base + 4] = o1;
    }
}

extern "C" void kernel_launch(void* const* d_in, const int* in_sizes, int n_in,
                              void* d_out, int out_size, void* d_ws, size_t ws_size,
                              hipStream_t stream) {
    const float* x = (const float*)d_in[0];
    const float* edge = (const float*)d_in[1];
    const float* Ws = (const float*)d_in[2];
    const float* bs = (const float*)d_in[3];
    const float* Wp = (const float*)d_in[4];
    const float* bp = (const float*)d_in[5];
    const float* W1 = (const float*)d_in[6];
    const float* W2 = (const float*)d_in[7];
    const float* We = (const float*)d_in[8];
    const float* gamma = (const float*)d_in[9];
    const float* beta = (const float*)d_in[10];
    float* out = (float*)d_out;

    float* ws = (float*)d_ws;
    float* gate = ws;                       // 73728
    float* xs = gate + 73728;               // 4718592
    float* pc = xs + 4718592;               // 4718592
    float* xn = pc + 4718592;               // 65536
    float* G = xn + 65536;                  // 65536
    float* M = G + 65536;                   // 262144
    float* sc = M + 262144;                 // 256
    float* bi = sc + 256;                   // 256  (total ~39.6 MB)

    hipMemsetAsync(xn, 0, 2 * 65536 * sizeof(float), stream);   // xn + G
    k_gate<<<288, 256, 0, stream>>>(edge, gate);
    k_proj<<<dim3(72, 16), 256, 0, stream>>>(x, Ws, bs, Wp, bp, gate, xs, pc);
    k_softmax<<<1024, 256, 0, stream>>>(pc);
    k_graph<<<dim3(8, 16), 256, 0, stream>>>(xs, pc, xn, G);
    k_gcn<<<16, 256, 0, stream>>>(xn, W1, W2, We, M);
    k_stats<<<256, 256, 0, stream>>>(M, G, gamma, beta, sc, bi);
    k_out<<<dim3(36, 4, 16), 256, 0, stream>>>(x, M, pc, sc, bi, out);
}

// Round 2
// 309.431 us; speedup vs baseline: 1.1338x; 1.1338x over previous
//
#include <hip/hip_runtime.h>

#define HW 4608      // 48*96
#define NB 16        // batch
#define CC 256       // channels
#define SS 64        // states
#define EPS 1e-5f

// ---------------- K0: transpose weights -> Wc[c][r], r<64: Ws, r>=64: Wp ----------------
__global__ __launch_bounds__(256) void k_transw(const float* __restrict__ Ws,
                                                const float* __restrict__ Wp,
                                                float* __restrict__ Wc) {
    int idx = blockIdx.x * 256 + threadIdx.x;    // 0..32767
    int c = idx >> 7, r = idx & 127;
    Wc[idx] = (r < 64) ? Ws[r * CC + c] : Wp[(r - 64) * CC + c];
}

// ---------------- K1: xs = Ws@x + bs ; E = exp((Wp@x + bp)*(1+gate)) ----------------
// grid (72, NB), block 256. Tile 64 k x 128 r; thread 8r x 4k.
__global__ __launch_bounds__(256) void k_proj(const float* __restrict__ x,
                                              const float* __restrict__ Wc,
                                              const float* __restrict__ bs,
                                              const float* __restrict__ bp,
                                              const float* __restrict__ edge,
                                              float* __restrict__ xs,
                                              float* __restrict__ E) {
    __shared__ __align__(16) float xt[16][64];    // [cc][k]
    __shared__ __align__(16) float wt[16][128];   // [cc][r]
    int n = blockIdx.y;
    int k0 = blockIdx.x * 64;
    int tid = threadIdx.x;
    int tr = tid >> 4, tk = tid & 15;
    float acc[8][4] = {};
    for (int c0 = 0; c0 < CC; c0 += 16) {
        {   // stage x: 1024 floats, 1 float4/thread, coalesced, conflict-free
            int cc = tid >> 4, kl = (tid & 15) * 4;
            *(float4*)&xt[cc][kl] =
                *(const float4*)&x[((size_t)n * CC + c0 + cc) * HW + k0 + kl];
        }
#pragma unroll
        for (int i = 0; i < 2; i++) {  // stage W: 2048 floats
            int idx = tid + i * 256;               // 0..511
            int cc = idx >> 5, r4 = (idx & 31) * 4;
            *(float4*)&wt[cc][r4] = *(const float4*)&Wc[(c0 + cc) * 128 + r4];
        }
        __syncthreads();
#pragma unroll
        for (int cc = 0; cc < 16; cc++) {
            float4 xv = *(const float4*)&xt[cc][tk * 4];
            float4 w0 = *(const float4*)&wt[cc][tr * 8];
            float4 w1 = *(const float4*)&wt[cc][tr * 8 + 4];
            float xa[4] = {xv.x, xv.y, xv.z, xv.w};
            float wa[8] = {w0.x, w0.y, w0.z, w0.w, w1.x, w1.y, w1.z, w1.w};
#pragma unroll
            for (int i = 0; i < 8; i++)
#pragma unroll
                for (int j = 0; j < 4; j++) acc[i][j] += wa[i] * xa[j];
        }
        __syncthreads();
    }
    // epilogue: rows tr*8..tr*8+7 (tr<8 -> xs branch, tr>=8 -> E branch), cols k0+tk*4
    size_t kcol = k0 + tk * 4;
    if (tr < 8) {
#pragma unroll
        for (int i = 0; i < 8; i++) {
            int s = tr * 8 + i;
            float bv = bs[s];
            float4 o = {acc[i][0] + bv, acc[i][1] + bv, acc[i][2] + bv, acc[i][3] + bv};
            *(float4*)&xs[((size_t)n * SS + s) * HW + kcol] = o;
        }
    } else {
        float4 e0 = *(const float4*)&edge[(size_t)(n * 2 + 0) * HW + kcol];
        float4 e1 = *(const float4*)&edge[(size_t)(n * 2 + 1) * HW + kcol];
        float ga[4];
        ga[0] = 1.f + 1.f / (1.f + __expf(e0.x - e1.x));
        ga[1] = 1.f + 1.f / (1.f + __expf(e0.y - e1.y));
        ga[2] = 1.f + 1.f / (1.f + __expf(e0.z - e1.z));
        ga[3] = 1.f + 1.f / (1.f + __expf(e0.w - e1.w));
#pragma unroll
        for (int i = 0; i < 8; i++) {
            int s = (tr - 8) * 8 + i;
            float bv = bp[s];
            float4 o;
            o.x = __expf((acc[i][0] + bv) * ga[0]);
            o.y = __expf((acc[i][1] + bv) * ga[1]);
            o.z = __expf((acc[i][2] + bv) * ga[2]);
            o.w = __expf((acc[i][3] + bv) * ga[3]);
            *(float4*)&E[((size_t)n * SS + s) * HW + kcol] = o;
        }
    }
}

// ---------------- K2: U = xs@E^T, P = E@E^T, rsum = E@1 (split-K, atomics) ----------------
// grid (16, NB): 288 k per block = 9 chunks of 32.
__global__ __launch_bounds__(256) void k_graph(const float* __restrict__ xs,
                                               const float* __restrict__ E,
                                               float* __restrict__ U,
                                               float* __restrict__ P,
                                               float* __restrict__ rsum) {
    __shared__ __align__(16) float xsT[32 * 68];
    __shared__ __align__(16) float cbT[32 * 68];
    int n = blockIdx.y;
    int k0 = blockIdx.x * 288;
    int tid = threadIdx.x;
    int ts = tid >> 4, tk = tid & 15;
    int sr = tid & 63, qr = tid >> 6;     // for rowsum accumulation
    float aU[4][4] = {};
    float aP[4][4] = {};
    float rsAcc = 0.f;
    for (int sub = 0; sub < 9; sub++) {
        int kb = k0 + sub * 32;
#pragma unroll
        for (int i = 0; i < 8; i++) {
            int idx = tid + i * 256;            // 0..2047
            int s = idx >> 5, kk = idx & 31;
            size_t off = ((size_t)n * SS + s) * HW + kb + kk;
            xsT[kk * 68 + s] = xs[off];
            cbT[kk * 68 + s] = E[off];
        }
        __syncthreads();
#pragma unroll
        for (int kk = 0; kk < 8; kk++)
            rsAcc += cbT[(qr * 8 + kk) * 68 + sr];
#pragma unroll
        for (int kk = 0; kk < 32; kk++) {
            float4 a4 = *(const float4*)&xsT[kk * 68 + ts * 4];
            float4 b4 = *(const float4*)&cbT[kk * 68 + tk * 4];
            float4 c4 = *(const float4*)&cbT[kk * 68 + ts * 4];
            float a[4] = {a4.x, a4.y, a4.z, a4.w};
            float b[4] = {b4.x, b4.y, b4.z, b4.w};
            float c[4] = {c4.x, c4.y, c4.z, c4.w};
#pragma unroll
            for (int i = 0; i < 4; i++)
#pragma unroll
                for (int j = 0; j < 4; j++) {
                    aU[i][j] += a[i] * b[j];
                    aP[i][j] += c[i] * b[j];
                }
        }
        __syncthreads();
    }
    atomicAdd(&rsum[n * SS + sr], rsAcc);
#pragma unroll
    for (int i = 0; i < 4; i++)
#pragma unroll
        for (int j = 0; j < 4; j++) {
            int o = n * 4096 + (ts * 4 + i) * 64 + tk * 4 + j;
            atomicAdd(&U[o], aU[i][j]);
            atomicAdd(&P[o], aP[i][j]);
        }
}

// ---------------- K3: GCN + fold We:  M'[n] = (We @ relu(W2 @ (xn@W1^T - xn))) / rsum ----------------
// grid (NB, 4): phases 1-2 recomputed per block; phase 3 chunk cc only.
__global__ __launch_bounds__(256) void k_gcn(const float* __restrict__ U,
                                             const float* __restrict__ rsum,
                                             const float* __restrict__ W1,
                                             const float* __restrict__ W2,
                                             const float* __restrict__ We,
                                             float* __restrict__ M) {
    __shared__ __align__(16) float A[64 * 68];
    __shared__ __align__(16) float B[64 * 68];
    __shared__ __align__(16) float Cb[64 * 68];
    __shared__ float rs[64];
    int n = blockIdx.x;
    int cc = blockIdx.y;
    int tid = threadIdx.x;
    int t0 = tid >> 4, t1 = tid & 15;
    if (tid < 64) rs[tid] = 1.0f / rsum[n * SS + tid];
    __syncthreads();
    // A[j][s] = xn[s][j] = U[s][j]*rinv[j] ; B[j][i] = W1[i][j]
#pragma unroll
    for (int i = 0; i < 16; i++) {
        int idx = tid + i * 256;               // 0..4095
        int r = idx >> 6, cth = idx & 63;
        A[cth * 68 + r] = U[n * 4096 + idx] * rs[cth];
        B[cth * 68 + r] = W1[idx];
    }
    __syncthreads();
    // phase1: Cb[s][i] = sum_j A[j][s]*B[j][i] - xn[s][i]
    {
        float acc[4][4] = {};
        for (int j = 0; j < 64; j++) {
            float4 a4 = *(const float4*)&A[j * 68 + t0 * 4];
            float4 b4 = *(const float4*)&B[j * 68 + t1 * 4];
            float a[4] = {a4.x, a4.y, a4.z, a4.w};
            float b[4] = {b4.x, b4.y, b4.z, b4.w};
#pragma unroll
            for (int p = 0; p < 4; p++)
#pragma unroll
                for (int q = 0; q < 4; q++) acc[p][q] += a[p] * b[q];
        }
#pragma unroll
        for (int p = 0; p < 4; p++)
#pragma unroll
            for (int q = 0; q < 4; q++) {
                acc[p][q] -= A[(t1 * 4 + q) * 68 + (t0 * 4 + p)];
                Cb[(t0 * 4 + p) * 68 + t1 * 4 + q] = acc[p][q];
            }
    }
    __syncthreads();
    // B[j][i] = W2[i][j]
#pragma unroll
    for (int i = 0; i < 16; i++) {
        int idx = tid + i * 256;
        int r = idx >> 6, cth = idx & 63;
        B[cth * 68 + r] = W2[idx];
    }
    __syncthreads();
    // phase2: A[i][k] = relu(sum_j B[j][i]*Cb[j][k])
    {
        float acc[4][4] = {};
        for (int j = 0; j < 64; j++) {
            float4 a4 = *(const float4*)&B[j * 68 + t0 * 4];
            float4 b4 = *(const float4*)&Cb[j * 68 + t1 * 4];
            float a[4] = {a4.x, a4.y, a4.z, a4.w};
            float b[4] = {b4.x, b4.y, b4.z, b4.w};
#pragma unroll
            for (int p = 0; p < 4; p++)
#pragma unroll
                for (int q = 0; q < 4; q++) acc[p][q] += a[p] * b[q];
        }
        __syncthreads();
#pragma unroll
        for (int p = 0; p < 4; p++)
#pragma unroll
            for (int q = 0; q < 4; q++)
                A[(t0 * 4 + p) * 68 + t1 * 4 + q] = fmaxf(acc[p][q], 0.f);
    }
    __syncthreads();
    // phase3 (chunk cc): M'[c][t] = (sum_j We[c][j]*h2[j][t]) * rinv[t]
#pragma unroll
    for (int i = 0; i < 16; i++) {
        int idx = tid + i * 256;
        int c = idx >> 6, j = idx & 63;
        B[j * 68 + c] = We[(cc * 64 + c) * 64 + j];
    }
    __syncthreads();
    {
        float acc[4][4] = {};
        for (int j = 0; j < 64; j++) {
            float4 a4 = *(const float4*)&B[j * 68 + t0 * 4];
            float4 b4 = *(const float4*)&A[j * 68 + t1 * 4];
            float a[4] = {a4.x, a4.y, a4.z, a4.w};
            float b[4] = {b4.x, b4.y, b4.z, b4.w};
#pragma unroll
            for (int p = 0; p < 4; p++)
#pragma unroll
                for (int q = 0; q < 4; q++) acc[p][q] += a[p] * b[q];
        }
#pragma unroll
        for (int p = 0; p < 4; p++) {
            float4 st;
            st.x = acc[p][0] * rs[t1 * 4 + 0];
            st.y = acc[p][1] * rs[t1 * 4 + 1];
            st.z = acc[p][2] * rs[t1 * 4 + 2];
            st.w = acc[p][3] * rs[t1 * 4 + 3];
            *(float4*)&M[((size_t)n * CC + cc * 64 + t0 * 4 + p) * 64 + t1 * 4] = st;
        }
    }
}

// ---------------- K4: BN stats -> scale/bias ----------------
// sum_k ext = sum_t M'[c][t]*rsum[t] ; sum_k ext^2 = m'^T P m'. grid CC.
__global__ __launch_bounds__(256) void k_stats(const float* __restrict__ M,
                                               const float* __restrict__ P,
                                               const float* __restrict__ rsum,
                                               const float* __restrict__ gamma,
                                               const float* __restrict__ beta,
                                               float* __restrict__ sc,
                                               float* __restrict__ bi) {
    __shared__ float ms[64];
    __shared__ float rst[64];
    __shared__ float red[256];
    int c = blockIdx.x;
    int tid = threadIdx.x;
    float qa = 0.f, sa = 0.f;
    for (int n = 0; n < NB; n++) {
        if (tid < 64) ms[tid] = M[((size_t)n * CC + c) * 64 + tid];
        else if (tid < 128) rst[tid - 64] = rsum[n * SS + tid - 64];
        __syncthreads();
#pragma unroll
        for (int p = 0; p < 16; p++) {
            int e = p * 256 + tid;
            qa += ms[e >> 6] * ms[e & 63] * P[n * 4096 + e];
        }
        if ((tid & 63) == 0) {
#pragma unroll
            for (int p = 0; p < 16; p++) {
                int s = (p * 256 + tid) >> 6;
                sa += ms[s] * rst[s];
            }
        }
        __syncthreads();
    }
    red[tid] = qa;
    __syncthreads();
    for (int off = 128; off > 0; off >>= 1) {
        if (tid < off) red[tid] += red[tid + off];
        __syncthreads();
    }
    float qtot = red[0];
    __syncthreads();
    red[tid] = sa;
    __syncthreads();
    for (int off = 128; off > 0; off >>= 1) {
        if (tid < off) red[tid] += red[tid + off];
        __syncthreads();
    }
    float stot = red[0];
    if (tid == 0) {
        const float invM = 1.0f / ((float)NB * (float)HW);
        float mean = stot * invM;
        float var = qtot * invM - mean * mean;
        float s = gamma[c] * rsqrtf(var + EPS);
        sc[c] = s;
        bi[c] = beta[c] - s * mean;
    }
}

// ---------------- K5: out = x + sc[c]*(M' @ E)[c,k] + bi[c] ----------------
// grid (36, 4, NB): 128 k x 64 c tile; thread 4c x (4+4)k split cols tk*4 and 64+tk*4.
__global__ __launch_bounds__(256) void k_out(const float* __restrict__ x,
                                             const float* __restrict__ M,
                                             const float* __restrict__ E,
                                             const float* __restrict__ sc,
                                             const float* __restrict__ bi,
                                             float* __restrict__ out) {
    __shared__ __align__(16) float MT[16 * 68];
    __shared__ __align__(16) float cb[16 * 128];
    int k0 = blockIdx.x * 128;
    int c0 = blockIdx.y * 64;
    int n = blockIdx.z;
    int tid = threadIdx.x;
    int tc = tid >> 4, tk = tid & 15;
    float acc[4][8] = {};
    for (int s0 = 0; s0 < 64; s0 += 16) {
#pragma unroll
        for (int i = 0; i < 4; i++) {
            int idx = tid + i * 256;              // 0..1023
            int cL = idx >> 4, sj = idx & 15;
            MT[sj * 68 + cL] = M[((size_t)n * CC + c0 + cL) * 64 + s0 + sj];
        }
#pragma unroll
        for (int i = 0; i < 8; i++) {
            int idx = tid + i * 256;              // 0..2047
            int sj = idx >> 7, kk = idx & 127;
            cb[sj * 128 + kk] = E[((size_t)n * SS + s0 + sj) * HW + k0 + kk];
        }
        __syncthreads();
#pragma unroll
        for (int sj = 0; sj < 16; sj++) {
            float4 a4 = *(const float4*)&MT[sj * 68 + tc * 4];
            float4 b0 = *(const float4*)&cb[sj * 128 + tk * 4];
            float4 b1 = *(const float4*)&cb[sj * 128 + 64 + tk * 4];
            float a[4] = {a4.x, a4.y, a4.z, a4.w};
            float b[8] = {b0.x, b0.y, b0.z, b0.w, b1.x, b1.y, b1.z, b1.w};
#pragma unroll
            for (int i = 0; i < 4; i++)
#pragma unroll
                for (int j = 0; j < 8; j++) acc[i][j] += a[i] * b[j];
        }
        __syncthreads();
    }
#pragma unroll
    for (int i = 0; i < 4; i++) {
        int c = c0 + tc * 4 + i;
        float s = sc[c], bv = bi[c];
        size_t base = ((size_t)n * CC + c) * HW + k0 + tk * 4;
        float4 x0 = *(const float4*)&x[base];
        float4 x1 = *(const float4*)&x[base + 64];
        float4 o0, o1;
        o0.x = x0.x + s * acc[i][0] + bv;
        o0.y = x0.y + s * acc[i][1] + bv;
        o0.z = x0.z + s * acc[i][2] + bv;
        o0.w = x0.w + s * acc[i][3] + bv;
        o1.x = x1.x + s * acc[i][4] + bv;
        o1.y = x1.y + s * acc[i][5] + bv;
        o1.z = x1.z + s * acc[i][6] + bv;
        o1.w = x1.w + s * acc[i][7] + bv;
        *(float4*)&out[base] = o0;
        *(float4*)&out[base + 64] = o1;
    }
}

extern "C" void kernel_launch(void* const* d_in, const int* in_sizes, int n_in,
                              void* d_out, int out_size, void* d_ws, size_t ws_size,
                              hipStream_t stream) {
    const float* x = (const float*)d_in[0];
    const float* edge = (const float*)d_in[1];
    const float* Ws = (const float*)d_in[2];
    const float* bs = (const float*)d_in[3];
    const float* Wp = (const float*)d_in[4];
    const float* bp = (const float*)d_in[5];
    const float* W1 = (const float*)d_in[6];
    const float* W2 = (const float*)d_in[7];
    const float* We = (const float*)d_in[8];
    const float* gamma = (const float*)d_in[9];
    const float* beta = (const float*)d_in[10];
    float* out = (float*)d_out;

    float* ws = (float*)d_ws;
    float* Wc = ws;                         // 32768
    float* xs = Wc + 32768;                 // 4718592
    float* E  = xs + 4718592;               // 4718592
    float* U  = E + 4718592;                // 65536
    float* P  = U + 65536;                  // 65536
    float* rsum = P + 65536;                // 1024
    float* M  = rsum + 1024;                // 262144
    float* sc = M + 262144;                 // 256
    float* bi = sc + 256;                   // 256   total ~39.5 MB

    hipMemsetAsync(U, 0, (2 * 65536 + 1024) * sizeof(float), stream);  // U, P, rsum
    k_transw<<<128, 256, 0, stream>>>(Ws, Wp, Wc);
    k_proj<<<dim3(72, 16), 256, 0, stream>>>(x, Wc, bs, bp, edge, xs, E);
    k_graph<<<dim3(16, 16), 256, 0, stream>>>(xs, E, U, P, rsum);
    k_gcn<<<dim3(16, 4), 256, 0, stream>>>(U, rsum, W1, W2, We, M);
    k_stats<<<256, 256, 0, stream>>>(M, P, rsum, gamma, beta, sc, bi);
    k_out<<<dim3(36, 4, 16), 256, 0, stream>>>(x, M, E, sc, bi, out);
}

// Round 3
// 235.802 us; speedup vs baseline: 1.4878x; 1.3122x over previous
//
#include <hip/hip_runtime.h>

#define HW 4608      // 48*96
#define NB 16
#define CC 256
#define SS 64
#define EPS 1e-5f
#define NSPLIT 24    // k_graph split-K

typedef __attribute__((ext_vector_type(8))) short short8;
typedef __attribute__((ext_vector_type(4))) float f32x4;

__device__ __forceinline__ ushort f2bf(float f) {
    uint u = __float_as_uint(f);
    return (ushort)((u + 0x7FFFu + ((u >> 16) & 1u)) >> 16);
}
__device__ __forceinline__ float bf2f(ushort h) {
    return __uint_as_float(((uint)h) << 16);
}

// ---------------- K0: pack W fragment-ready: Wf[cs][kq][r][j] bf16, c = cs*32+kq*8+j ----------
__global__ __launch_bounds__(256) void k_wf(const float* __restrict__ Ws,
                                            const float* __restrict__ Wp,
                                            ushort* __restrict__ Wf) {
    int idx = blockIdx.x * 256 + threadIdx.x;      // 0..32767
    int j = idx & 7, r = (idx >> 3) & 127, kq = (idx >> 10) & 3, cs = idx >> 12;
    int c = cs * 32 + kq * 8 + j;
    float v = (r < 64) ? Ws[r * CC + c] : Wp[(r - 64) * CC + c];
    Wf[idx] = f2bf(v);
}

// ---------------- K1: MFMA proj: [xs;E](128 x HW) = Wc @ x ; E=exp(gated); rsum atomics ------
// grid (36, NB), 256 thr (4 waves, 2x2). Block tile 128r x 128k, K=C=256 in 8 steps.
__global__ __launch_bounds__(256) void k_proj(const float* __restrict__ x,
                                              const ushort* __restrict__ Wf,
                                              const float* __restrict__ bs,
                                              const float* __restrict__ bp,
                                              const float* __restrict__ edge,
                                              ushort* __restrict__ xsb,
                                              ushort* __restrict__ Eb,
                                              float* __restrict__ rsum) {
    __shared__ __align__(16) ushort Bl[4 * 128 * 8];   // [kq][n][8] = 8 KB
    int n = blockIdx.y, k0 = blockIdx.x * 128;
    int tid = threadIdx.x, lane = tid & 63, w = tid >> 6;
    int wr = w >> 1, wn = w & 1;
    int q = lane >> 4, li = lane & 15;
    int sn = tid & 127, kq0 = (tid >> 7) * 2;
    f32x4 acc[4][4] = {};
    for (int cs = 0; cs < 8; cs++) {
        // stage x (fp32 -> bf16 fragment layout), conflict-free b128 writes
#pragma unroll
        for (int kk = 0; kk < 2; kk++) {
            int kq = kq0 + kk;
            union { ushort u[8]; uint4 v; } tmp;
#pragma unroll
            for (int j = 0; j < 8; j++) {
                float vv = x[((size_t)n * CC + cs * 32 + kq * 8 + j) * HW + k0 + sn];
                tmp.u[j] = f2bf(vv);
            }
            *(uint4*)&Bl[(kq * 128 + sn) * 8] = tmp.v;
        }
        __syncthreads();
        short8 af[4], bfr[4];
#pragma unroll
        for (int m = 0; m < 4; m++) {       // a-frags direct from global Wf (L2-hot)
            int r = wr * 64 + m * 16 + li;
            uint4 t = *(const uint4*)&Wf[((cs * 4 + q) * 128 + r) * 8];
            af[m] = *(short8*)&t;
        }
#pragma unroll
        for (int nn = 0; nn < 4; nn++) {
            int nl = wn * 64 + nn * 16 + li;
            uint4 t = *(const uint4*)&Bl[(q * 128 + nl) * 8];
            bfr[nn] = *(short8*)&t;
        }
#pragma unroll
        for (int m = 0; m < 4; m++)
#pragma unroll
            for (int nn = 0; nn < 4; nn++)
                acc[m][nn] = __builtin_amdgcn_mfma_f32_16x16x32_bf16(af[m], bfr[nn], acc[m][nn], 0, 0, 0);
        __syncthreads();
    }
    // epilogue: rows wr*64 + m*16 + q*4 + rr ; cols k0 + wn*64 + nn*16 + li
    if (wr == 0) {
#pragma unroll
        for (int m = 0; m < 4; m++) {
#pragma unroll
            for (int rr = 0; rr < 4; rr++) {
                int s = m * 16 + q * 4 + rr;
                float bv = bs[s];
#pragma unroll
                for (int nn = 0; nn < 4; nn++) {
                    int col = k0 + wn * 64 + nn * 16 + li;
                    xsb[((size_t)n * SS + s) * HW + col] = f2bf(acc[m][nn][rr] + bv);
                }
            }
        }
    } else {
        float ga[4];
#pragma unroll
        for (int nn = 0; nn < 4; nn++) {
            int col = k0 + wn * 64 + nn * 16 + li;
            float e0 = edge[((size_t)n * 2 + 0) * HW + col];
            float e1 = edge[((size_t)n * 2 + 1) * HW + col];
            ga[nn] = 1.f + 1.f / (1.f + __expf(e0 - e1));
        }
        float rp[4][4];
#pragma unroll
        for (int m = 0; m < 4; m++) {
#pragma unroll
            for (int rr = 0; rr < 4; rr++) {
                int s = m * 16 + q * 4 + rr;
                float bv = bp[s];
                float sum = 0.f;
#pragma unroll
                for (int nn = 0; nn < 4; nn++) {
                    int col = k0 + wn * 64 + nn * 16 + li;
                    float e = __expf((acc[m][nn][rr] + bv) * ga[nn]);
                    sum += e;
                    Eb[((size_t)n * SS + s) * HW + col] = f2bf(e);
                }
                rp[m][rr] = sum;
            }
        }
#pragma unroll
        for (int b = 1; b < 16; b <<= 1)
#pragma unroll
            for (int m = 0; m < 4; m++)
#pragma unroll
                for (int rr = 0; rr < 4; rr++)
                    rp[m][rr] += __shfl_xor(rp[m][rr], b, 64);
        if (li == 0) {
#pragma unroll
            for (int m = 0; m < 4; m++)
#pragma unroll
                for (int rr = 0; rr < 4; rr++)
                    atomicAdd(&rsum[n * SS + m * 16 + q * 4 + rr], rp[m][rr]);
        }
    }
}

// ---------------- K2: MFMA graph: U = xs@E^T, P = E@E^T, split-K partials, NO LDS -----------
// grid (NSPLIT, NB). Waves 0,1: U halves; waves 2,3: P halves. K/block = HW/NSPLIT = 192.
__global__ __launch_bounds__(256) void k_graph(const ushort* __restrict__ xsb,
                                               const ushort* __restrict__ Eb,
                                               float* __restrict__ Up,
                                               float* __restrict__ Pp) {
    int n = blockIdx.y, sp = blockIdx.x;
    int kbase = sp * (HW / NSPLIT);
    int tid = threadIdx.x, lane = tid & 63, w = tid >> 6;
    int q = lane >> 4, li = lane & 15;
    bool isP = w >= 2;
    int half = w & 1;
    const ushort* Arow = isP ? Eb : xsb;
    f32x4 acc[2][4] = {};
    for (int ks = 0; ks < (HW / NSPLIT) / 32; ks++) {
        int kb = kbase + ks * 32 + q * 8;
        short8 af[2], bfr[4];
#pragma unroll
        for (int mt = 0; mt < 2; mt++) {
            int s = half * 32 + mt * 16 + li;
            uint4 t = *(const uint4*)&Arow[((size_t)n * SS + s) * HW + kb];
            af[mt] = *(short8*)&t;
        }
#pragma unroll
        for (int nt = 0; nt < 4; nt++) {
            int tt = nt * 16 + li;
            uint4 t = *(const uint4*)&Eb[((size_t)n * SS + tt) * HW + kb];
            bfr[nt] = *(short8*)&t;
        }
#pragma unroll
        for (int mt = 0; mt < 2; mt++)
#pragma unroll
            for (int nt = 0; nt < 4; nt++)
                acc[mt][nt] = __builtin_amdgcn_mfma_f32_16x16x32_bf16(af[mt], bfr[nt], acc[mt][nt], 0, 0, 0);
    }
    float* dst = (isP ? Pp : Up) + ((size_t)sp * NB + n) * 4096;
#pragma unroll
    for (int mt = 0; mt < 2; mt++)
#pragma unroll
        for (int nt = 0; nt < 4; nt++)
#pragma unroll
            for (int rr = 0; rr < 4; rr++) {
                int row = half * 32 + mt * 16 + q * 4 + rr;
                int col = nt * 16 + li;
                dst[row * 64 + col] = acc[mt][nt][rr];
            }
}

// ---------------- K2b: reduce split-K partials ----------------
__global__ __launch_bounds__(256) void k_red(const float* __restrict__ Up,
                                             const float* __restrict__ Pp,
                                             float* __restrict__ U,
                                             float* __restrict__ P) {
    int idx = blockIdx.x * 256 + threadIdx.x;    // 0..131071
    const float* src = (idx < 65536) ? Up : Pp;
    float* dst = (idx < 65536) ? U : P;
    int o = idx & 65535;
    float s = 0.f;
    for (int sp = 0; sp < NSPLIT; sp++) s += src[(size_t)sp * 65536 + o];
    dst[o] = s;
}

// ---------------- K3: GCN + fold We: M' fp32 [c][t] AND bf16 fragment-ready Mf --------------
__global__ __launch_bounds__(256) void k_gcn(const float* __restrict__ U,
                                             const float* __restrict__ rsum,
                                             const float* __restrict__ W1,
                                             const float* __restrict__ W2,
                                             const float* __restrict__ We,
                                             float* __restrict__ M,
                                             ushort* __restrict__ Mf) {
    __shared__ __align__(16) float A[64 * 68];
    __shared__ __align__(16) float B[64 * 68];
    __shared__ __align__(16) float Cb[64 * 68];
    __shared__ float rs[64];
    int n = blockIdx.x;
    int cc = blockIdx.y;
    int tid = threadIdx.x;
    int t0 = tid >> 4, t1 = tid & 15;
    if (tid < 64) rs[tid] = 1.0f / rsum[n * SS + tid];
    __syncthreads();
#pragma unroll
    for (int i = 0; i < 16; i++) {
        int idx = tid + i * 256;
        int r = idx >> 6, cth = idx & 63;
        A[cth * 68 + r] = U[n * 4096 + idx] * rs[cth];
        B[cth * 68 + r] = W1[idx];
    }
    __syncthreads();
    {
        float acc[4][4] = {};
        for (int j = 0; j < 64; j++) {
            float4 a4 = *(const float4*)&A[j * 68 + t0 * 4];
            float4 b4 = *(const float4*)&B[j * 68 + t1 * 4];
            float a[4] = {a4.x, a4.y, a4.z, a4.w};
            float b[4] = {b4.x, b4.y, b4.z, b4.w};
#pragma unroll
            for (int p = 0; p < 4; p++)
#pragma unroll
                for (int qq = 0; qq < 4; qq++) acc[p][qq] += a[p] * b[qq];
        }
#pragma unroll
        for (int p = 0; p < 4; p++)
#pragma unroll
            for (int qq = 0; qq < 4; qq++) {
                acc[p][qq] -= A[(t1 * 4 + qq) * 68 + (t0 * 4 + p)];
                Cb[(t0 * 4 + p) * 68 + t1 * 4 + qq] = acc[p][qq];
            }
    }
    __syncthreads();
#pragma unroll
    for (int i = 0; i < 16; i++) {
        int idx = tid + i * 256;
        int r = idx >> 6, cth = idx & 63;
        B[cth * 68 + r] = W2[idx];
    }
    __syncthreads();
    {
        float acc[4][4] = {};
        for (int j = 0; j < 64; j++) {
            float4 a4 = *(const float4*)&B[j * 68 + t0 * 4];
            float4 b4 = *(const float4*)&Cb[j * 68 + t1 * 4];
            float a[4] = {a4.x, a4.y, a4.z, a4.w};
            float b[4] = {b4.x, b4.y, b4.z, b4.w};
#pragma unroll
            for (int p = 0; p < 4; p++)
#pragma unroll
                for (int qq = 0; qq < 4; qq++) acc[p][qq] += a[p] * b[qq];
        }
        __syncthreads();
#pragma unroll
        for (int p = 0; p < 4; p++)
#pragma unroll
            for (int qq = 0; qq < 4; qq++)
                A[(t0 * 4 + p) * 68 + t1 * 4 + qq] = fmaxf(acc[p][qq], 0.f);
    }
    __syncthreads();
#pragma unroll
    for (int i = 0; i < 16; i++) {
        int idx = tid + i * 256;
        int c = idx >> 6, j = idx & 63;
        B[j * 68 + c] = We[(cc * 64 + c) * 64 + j];
    }
    __syncthreads();
    {
        float acc[4][4] = {};
        for (int j = 0; j < 64; j++) {
            float4 a4 = *(const float4*)&B[j * 68 + t0 * 4];
            float4 b4 = *(const float4*)&A[j * 68 + t1 * 4];
            float a[4] = {a4.x, a4.y, a4.z, a4.w};
            float b[4] = {b4.x, b4.y, b4.z, b4.w};
#pragma unroll
            for (int p = 0; p < 4; p++)
#pragma unroll
                for (int qq = 0; qq < 4; qq++) acc[p][qq] += a[p] * b[qq];
        }
#pragma unroll
        for (int p = 0; p < 4; p++) {
            int c = cc * 64 + t0 * 4 + p;
            float v[4];
#pragma unroll
            for (int qq = 0; qq < 4; qq++) v[qq] = acc[p][qq] * rs[t1 * 4 + qq];
            float4 st = {v[0], v[1], v[2], v[3]};
            *(float4*)&M[((size_t)n * CC + c) * 64 + t1 * 4] = st;
#pragma unroll
            for (int qq = 0; qq < 4; qq++) {
                int t = t1 * 4 + qq;
                Mf[(size_t)n * 16384 + ((t >> 3) * 256 + c) * 8 + (t & 7)] = f2bf(v[qq]);
            }
        }
    }
}

// ---------------- K4: BN stats -> scale/bias ----------------
__global__ __launch_bounds__(256) void k_stats(const float* __restrict__ M,
                                               const float* __restrict__ P,
                                               const float* __restrict__ rsum,
                                               const float* __restrict__ gamma,
                                               const float* __restrict__ beta,
                                               float* __restrict__ sc,
                                               float* __restrict__ bi) {
    __shared__ float ms[64];
    __shared__ float rst[64];
    __shared__ float red[256];
    int c = blockIdx.x;
    int tid = threadIdx.x;
    float qa = 0.f, sa = 0.f;
    for (int n = 0; n < NB; n++) {
        if (tid < 64) ms[tid] = M[((size_t)n * CC + c) * 64 + tid];
        else if (tid < 128) rst[tid - 64] = rsum[n * SS + tid - 64];
        __syncthreads();
#pragma unroll
        for (int p = 0; p < 16; p++) {
            int e = p * 256 + tid;
            qa += ms[e >> 6] * ms[e & 63] * P[n * 4096 + e];
        }
        if ((tid & 63) == 0) {
#pragma unroll
            for (int p = 0; p < 16; p++) {
                int s = (p * 256 + tid) >> 6;
                sa += ms[s] * rst[s];
            }
        }
        __syncthreads();
    }
    red[tid] = qa;
    __syncthreads();
    for (int off = 128; off > 0; off >>= 1) {
        if (tid < off) red[tid] += red[tid + off];
        __syncthreads();
    }
    float qtot = red[0];
    __syncthreads();
    red[tid] = sa;
    __syncthreads();
    for (int off = 128; off > 0; off >>= 1) {
        if (tid < off) red[tid] += red[tid + off];
        __syncthreads();
    }
    float stot = red[0];
    if (tid == 0) {
        const float invM = 1.0f / ((float)NB * (float)HW);
        float mean = stot * invM;
        float var = qtot * invM - mean * mean;
        float s = gamma[c] * rsqrtf(var + EPS);
        sc[c] = s;
        bi[c] = beta[c] - s * mean;
    }
}

// ---------------- K5: MFMA out: out = x + sc[c]*(M' @ E)[c,k] + bi[c] ----------------
// grid (72, NB): block 256c x 64hw, K=64 (2 MFMA steps). A direct from Mf; B via LDS.
__global__ __launch_bounds__(256) void k_out(const float* __restrict__ x,
                                             const ushort* __restrict__ Mf,
                                             const ushort* __restrict__ Eb,
                                             const float* __restrict__ sc,
                                             const float* __restrict__ bi,
                                             float* __restrict__ out) {
    __shared__ __align__(16) ushort Bl[8 * 64 * 8];    // [kq][n][8] = 8 KB
    int n = blockIdx.y, k0 = blockIdx.x * 64;
    int tid = threadIdx.x, lane = tid & 63, w = tid >> 6;
    int q = lane >> 4, li = lane & 15;
    {
        int nl = tid & 63, pr = tid >> 6;
#pragma unroll
        for (int kk = 0; kk < 2; kk++) {
            int kq = pr * 2 + kk;
            union { ushort u[8]; uint4 v; } tmp;
#pragma unroll
            for (int j = 0; j < 8; j++)
                tmp.u[j] = Eb[((size_t)n * SS + kq * 8 + j) * HW + k0 + nl];
            *(uint4*)&Bl[(kq * 64 + nl) * 8] = tmp.v;
        }
    }
    __syncthreads();
    f32x4 acc[4][4] = {};
#pragma unroll
    for (int ks = 0; ks < 2; ks++) {
        short8 af[4], bfr[4];
#pragma unroll
        for (int mt = 0; mt < 4; mt++) {
            int c = w * 64 + mt * 16 + li;
            uint4 t = *(const uint4*)&Mf[(size_t)n * 16384 + ((ks * 4 + q) * 256 + c) * 8];
            af[mt] = *(short8*)&t;
        }
#pragma unroll
        for (int nt = 0; nt < 4; nt++) {
            int nl = nt * 16 + li;
            uint4 t = *(const uint4*)&Bl[((ks * 4 + q) * 64 + nl) * 8];
            bfr[nt] = *(short8*)&t;
        }
#pragma unroll
        for (int mt = 0; mt < 4; mt++)
#pragma unroll
            for (int nt = 0; nt < 4; nt++)
                acc[mt][nt] = __builtin_amdgcn_mfma_f32_16x16x32_bf16(af[mt], bfr[nt], acc[mt][nt], 0, 0, 0);
    }
#pragma unroll
    for (int mt = 0; mt < 4; mt++) {
#pragma unroll
        for (int rr = 0; rr < 4; rr++) {
            int c = w * 64 + mt * 16 + q * 4 + rr;
            float s_ = sc[c], bv = bi[c];
            size_t base = ((size_t)n * CC + c) * HW + k0;
#pragma unroll
            for (int nt = 0; nt < 4; nt++) {
                int col = nt * 16 + li;
                out[base + col] = x[base + col] + s_ * acc[mt][nt][rr] + bv;
            }
        }
    }
}

extern "C" void kernel_launch(void* const* d_in, const int* in_sizes, int n_in,
                              void* d_out, int out_size, void* d_ws, size_t ws_size,
                              hipStream_t stream) {
    const float* x = (const float*)d_in[0];
    const float* edge = (const float*)d_in[1];
    const float* Ws = (const float*)d_in[2];
    const float* bs = (const float*)d_in[3];
    const float* Wp = (const float*)d_in[4];
    const float* bp = (const float*)d_in[5];
    const float* W1 = (const float*)d_in[6];
    const float* W2 = (const float*)d_in[7];
    const float* We = (const float*)d_in[8];
    const float* gamma = (const float*)d_in[9];
    const float* beta = (const float*)d_in[10];
    float* out = (float*)d_out;

    char* base = (char*)d_ws;
    ushort* Wf  = (ushort*)base;                    base += 65536;           // 64 KB
    ushort* xsb = (ushort*)base;                    base += 9437184;         // 9 MB
    ushort* Eb  = (ushort*)base;                    base += 9437184;
    float*  Up  = (float*)base;                     base += (size_t)NSPLIT * NB * 4096 * 4;
    float*  Pp  = (float*)base;                     base += (size_t)NSPLIT * NB * 4096 * 4;
    float*  U   = (float*)base;                     base += 262144;
    float*  P   = (float*)base;                     base += 262144;
    float*  rsum= (float*)base;                     base += 4096;
    float*  M   = (float*)base;                     base += 1048576;
    ushort* Mf  = (ushort*)base;                    base += 524288;
    float*  sc  = (float*)base;                     base += 1024;
    float*  bi  = (float*)base;                     base += 1024;

    hipMemsetAsync(rsum, 0, 1024 * sizeof(float), stream);
    k_wf<<<128, 256, 0, stream>>>(Ws, Wp, Wf);
    k_proj<<<dim3(36, NB), 256, 0, stream>>>(x, Wf, bs, bp, edge, xsb, Eb, rsum);
    k_graph<<<dim3(NSPLIT, NB), 256, 0, stream>>>(xsb, Eb, Up, Pp);
    k_red<<<512, 256, 0, stream>>>(Up, Pp, U, P);
    k_gcn<<<dim3(NB, 4), 256, 0, stream>>>(U, rsum, W1, W2, We, M, Mf);
    k_stats<<<256, 256, 0, stream>>>(M, P, rsum, gamma, beta, sc, bi);
    k_out<<<dim3(72, NB), 256, 0, stream>>>(x, Mf, Eb, sc, bi, out);
}